// Round 1
// baseline (138.811 us; speedup 1.0000x reference)
//
#include <hip/hip_runtime.h>

// Fused NCA step: perchannel 3x3 conv (identity/sobelx/sobely/lap, circular pad)
// -> 1x1 conv(16->6)+relu -> tanh(1x1 6->4), sigmoid(1x1 6->4) -> gated blend.
// x: [16,4,512,512] f32. One thread = one (b,h, 4-wide w quad), all 4 channels.

constexpr int Bn = 16, Cn = 4, Hn = 512, Wn = 512, HIDDEN = 6;

__device__ __forceinline__ float fast_rcp(float v) { return __builtin_amdgcn_rcpf(v); }

__global__ __launch_bounds__(256) void nca_fused(
    const float* __restrict__ x,
    const float* __restrict__ w1w, const float* __restrict__ w1b,
    const float* __restrict__ w2w, const float* __restrict__ w2b,
    const float* __restrict__ w3w, const float* __restrict__ w3b,
    float* __restrict__ out)
{
    const int W4 = Wn / 4;                       // 128 quads per row
    int tid = blockIdx.x * 256 + threadIdx.x;
    int w4 = tid & (W4 - 1);
    int h  = (tid >> 7) & (Hn - 1);
    int b  = tid >> 16;

    int w0 = w4 << 2;
    int hm = (h == 0)      ? Hn - 1 : h - 1;     // circular pad
    int hp = (h == Hn - 1) ? 0      : h + 1;
    int wl = (w0 == 0)       ? Wn - 1 : w0 - 1;
    int wr = (w0 + 4 == Wn)  ? 0      : w0 + 4;

    const size_t plane = (size_t)Hn * Wn;
    const float* xb = x + (size_t)b * Cn * plane;

    // hid accumulators for 4 pixels, init with bias
    float acc[HIDDEN][4];
    #pragma unroll
    for (int o = 0; o < HIDDEN; ++o) {
        float bv = w1b[o];
        #pragma unroll
        for (int i = 0; i < 4; ++i) acc[o][i] = bv;
    }

    float xc[Cn][4];                             // center pixels (= identity map)

    #pragma unroll
    for (int c = 0; c < Cn; ++c) {
        const float* xp = xb + c * plane;
        const float* rt = xp + hm * Wn;
        const float* rm = xp + h  * Wn;
        const float* rb = xp + hp * Wn;
        float4 t4 = *(const float4*)(rt + w0);
        float4 m4 = *(const float4*)(rm + w0);
        float4 b4 = *(const float4*)(rb + w0);
        float t[6] = { rt[wl], t4.x, t4.y, t4.z, t4.w, rt[wr] };
        float m[6] = { rm[wl], m4.x, m4.y, m4.z, m4.w, rm[wr] };
        float d[6] = { rb[wl], b4.x, b4.y, b4.z, b4.w, rb[wr] };

        #pragma unroll
        for (int i = 0; i < 4; ++i) {
            float tL = t[i], tC = t[i+1], tR = t[i+2];
            float mL = m[i], mC = m[i+1], mR = m[i+2];
            float bL = d[i], bC = d[i+1], bR = d[i+2];
            // cross-correlation taps (XLA conv semantics, no kernel flip)
            float y0 = mC;                                               // identity
            float y1 = (tR - tL) + 2.f*(mR - mL) + (bR - bL);            // sobel_x
            float y2 = (bL - tL) + 2.f*(bC - tC) + (bR - tR);            // sobel_y
            float y3 = (tL + tR + bL + bR)
                     + 2.f*(tC + mL + mR + bC) - 12.f*mC;                // laplacian
            xc[c][i] = mC;
            #pragma unroll
            for (int o = 0; o < HIDDEN; ++o) {
                acc[o][i] = fmaf(w1w[o*16 + c*4 + 0], y0,
                            fmaf(w1w[o*16 + c*4 + 1], y1,
                            fmaf(w1w[o*16 + c*4 + 2], y2,
                            fmaf(w1w[o*16 + c*4 + 3], y3, acc[o][i]))));
            }
        }
    }

    #pragma unroll
    for (int o = 0; o < HIDDEN; ++o)
        #pragma unroll
        for (int i = 0; i < 4; ++i)
            acc[o][i] = fmaxf(acc[o][i], 0.f);   // relu

    float* ob = out + (size_t)b * Cn * plane + (size_t)h * Wn + w0;
    #pragma unroll
    for (int j = 0; j < Cn; ++j) {
        float res[4];
        #pragma unroll
        for (int i = 0; i < 4; ++i) {
            float u = w2b[j], g = w3b[j];
            #pragma unroll
            for (int o = 0; o < HIDDEN; ++o) {
                u = fmaf(w2w[j*HIDDEN + o], acc[o][i], u);
                g = fmaf(w3w[j*HIDDEN + o], acc[o][i], g);
            }
            // tanh(u) = 1 - 2/(exp(2u)+1); sigmoid(g) = 1/(1+exp(-g))
            float e2u = __expf(2.f * u);
            float th  = 1.f - 2.f * fast_rcp(e2u + 1.f);
            float sg  = fast_rcp(1.f + __expf(-g));
            res[i] = xc[j][i] * sg + (1.f - sg) * th;
        }
        *(float4*)(ob + j * plane) = make_float4(res[0], res[1], res[2], res[3]);
    }
}

extern "C" void kernel_launch(void* const* d_in, const int* in_sizes, int n_in,
                              void* d_out, int out_size, void* d_ws, size_t ws_size,
                              hipStream_t stream) {
    const float* x   = (const float*)d_in[0];
    // d_in[1] = filters — fixed identity/sobel/laplacian stack, hardcoded above
    const float* w1w = (const float*)d_in[2];
    const float* w1b = (const float*)d_in[3];
    const float* w2w = (const float*)d_in[4];
    const float* w2b = (const float*)d_in[5];
    const float* w3w = (const float*)d_in[6];
    const float* w3b = (const float*)d_in[7];
    float* out = (float*)d_out;

    int total  = Bn * Hn * (Wn / 4);             // 1,048,576 threads
    int blocks = total / 256;                    // 4096 blocks
    nca_fused<<<blocks, 256, 0, stream>>>(x, w1w, w1b, w2w, w2b, w3w, w3b, out);
}